// Round 11
// baseline (794.594 us; speedup 1.0000x reference)
//
#include <hip/hip_runtime.h>
#include <hip/hip_bf16.h>

#define HID 128
#define EDIM 16

typedef float v4f __attribute__((ext_vector_type(4)));
typedef float v2f __attribute__((ext_vector_type(2)));
typedef short s8v __attribute__((ext_vector_type(8)));   // 8 bf16 (4 VGPRs) MFMA frag
typedef float f4v __attribute__((ext_vector_type(4)));   // MFMA acc

#define MFMA_BF16(a, b, c) __builtin_amdgcn_mfma_f32_16x16x32_bf16((a), (b), (c), 0, 0, 0)

__device__ __forceinline__ unsigned short bf16_rne(float v)
{
    unsigned u = __builtin_bit_cast(unsigned, v);
    return (unsigned short)((u + 0x7fffu + ((u >> 16) & 1u)) >> 16);
}

__device__ __forceinline__ unsigned pack2(float lo, float hi)
{
    return (unsigned)bf16_rne(lo) | ((unsigned)bf16_rne(hi) << 16);
}

__device__ __forceinline__ float bflo(unsigned u) { return __builtin_bit_cast(float, u << 16); }
__device__ __forceinline__ float bfhi(unsigned u) { return __builtin_bit_cast(float, u & 0xffff0000u); }

__device__ __forceinline__ v2f unpack2(unsigned u)
{
    v2f r; r.x = bflo(u); r.y = bfhi(u); return r;
}

__device__ __forceinline__ void split_bf16(float v, unsigned short& h, unsigned short& l)
{
    unsigned u = __builtin_bit_cast(unsigned, v);
    unsigned hu = (u + 0x7fffu + ((u >> 16) & 1u)) >> 16;
    h = (unsigned short)hu;
    float hf = __builtin_bit_cast(float, hu << 16);
    l = bf16_rne(v - hf);
}

__device__ __forceinline__ v2f vmax0(v2f a)
{
    v2f r; r.x = fmaxf(a.x, 0.f); r.y = fmaxf(a.y, 0.f); return r;
}

// ================= CSR build =================
__global__ void hist_kernel(const int* __restrict__ dst, int* __restrict__ deg, int E)
{
    int e = blockIdx.x * 256 + threadIdx.x;
    if (e < E) atomicAdd(&deg[dst[e]], 1);
}

__global__ void block_sum_kernel(const int* __restrict__ deg, int* __restrict__ bsum, int Nn)
{
    int i = blockIdx.x * 256 + threadIdx.x;
    int v = (i < Nn) ? deg[i] : 0;
#pragma unroll
    for (int off = 32; off > 0; off >>= 1) v += __shfl_down(v, off, 64);
    __shared__ int ws[4];
    if ((threadIdx.x & 63) == 0) ws[threadIdx.x >> 6] = v;
    __syncthreads();
    if (threadIdx.x == 0) bsum[blockIdx.x] = ws[0] + ws[1] + ws[2] + ws[3];
}

__global__ void bsum_scan_kernel(int* bsum, int nb, int* total_out)
{
    __shared__ int sh[256];
    int tid = threadIdx.x;
    int v = (tid < nb) ? bsum[tid] : 0;
    sh[tid] = v;
    __syncthreads();
    for (int off = 1; off < 256; off <<= 1) {
        int tv = (tid >= off) ? sh[tid - off] : 0;
        __syncthreads();
        sh[tid] += tv;
        __syncthreads();
    }
    if (tid < nb) bsum[tid] = sh[tid] - v;
    if (tid == 255) *total_out = sh[255];
}

__global__ void block_scan_kernel(const int* __restrict__ deg, const int* __restrict__ bsum,
                                  int* __restrict__ row_start, int* __restrict__ cursor, int Nn)
{
    __shared__ int sh[256];
    int tid = threadIdx.x;
    int i = blockIdx.x * 256 + tid;
    int v = (i < Nn) ? deg[i] : 0;
    sh[tid] = v;
    __syncthreads();
    for (int off = 1; off < 256; off <<= 1) {
        int tv = (tid >= off) ? sh[tid - off] : 0;
        __syncthreads();
        sh[tid] += tv;
        __syncthreads();
    }
    if (i < Nn) {
        int excl = sh[tid] - v + bsum[blockIdx.x];
        row_start[i] = excl;
        cursor[i] = excl;
    }
}

// scatter + fused ea permute (fp32), nontemporal stores (no RFO)
template<bool COPY_EA>
__global__ void scatter_kernel(const int* __restrict__ src, const int* __restrict__ dst,
                               int* cursor, int* __restrict__ perm,
                               int* __restrict__ src_perm,
                               const float* __restrict__ ea, float* __restrict__ ea_perm,
                               int E)
{
    int e = blockIdx.x * 256 + threadIdx.x;
    if (e >= E) return;
    int pos = atomicAdd(&cursor[dst[e]], 1);
    __builtin_nontemporal_store(src[e], &src_perm[pos]);
    if (COPY_EA) {
        const v4f* s4 = (const v4f*)(ea + (size_t)e * EDIM);
        v4f a = s4[0], b = s4[1], c = s4[2], d = s4[3];
        v4f* dp = (v4f*)(ea_perm + (size_t)pos * EDIM);
        __builtin_nontemporal_store(a, dp);
        __builtin_nontemporal_store(b, dp + 1);
        __builtin_nontemporal_store(c, dp + 2);
        __builtin_nontemporal_store(d, dp + 3);
    } else {
        perm[pos] = e;
    }
}

// ================= weight prep: fp32 [K,128] -> transposed split-bf16 [128,K] hi/lo =================
__global__ void prep_weights(const float* __restrict__ Wp, const float* __restrict__ W1,
                             const float* __restrict__ W2, unsigned short* __restrict__ out)
{
    int idx = blockIdx.x * 256 + threadIdx.x;
    if (idx < 8192) {
        int n = idx >> 6, k = idx & 63;
        unsigned short h, l;
        split_bf16(Wp[k * 128 + n], h, l);
        out[idx] = h;
        out[8192 + idx] = l;
    } else {
        int j = idx - 8192;
        if (j >= 6 * 16384) return;
        int m2 = j >> 14;
        int r = j & 16383;
        int n = r >> 7, k = r & 127;
        int l = m2 >> 1;
        const float* Wsrc = (m2 & 1) ? (W2 + l * 16384) : (W1 + l * 16384);
        unsigned short h, lo;
        split_bf16(Wsrc[k * 128 + n], h, lo);
        int base = 16384 + m2 * 32768;
        out[base + r] = h;
        out[base + 16384 + r] = lo;
    }
}

// ====== Node-centric aggregation: 1 wave/node, 2 ch/lane; fp32 ea via scalar pipe, bf16 h gather ======
__device__ __forceinline__ void matvp(const v4f& a0, const v4f& a1,
                                      const v4f& a2, const v4f& a3,
                                      const v2f* __restrict__ w, v2f& m)
{
    m += w[0] * a0.x;  m += w[1] * a0.y;  m += w[2] * a0.z;  m += w[3] * a0.w;
    m += w[4] * a1.x;  m += w[5] * a1.y;  m += w[6] * a1.z;  m += w[7] * a1.w;
    m += w[8] * a2.x;  m += w[9] * a2.y;  m += w[10] * a2.z; m += w[11] * a2.w;
    m += w[12] * a3.x; m += w[13] * a3.y; m += w[14] * a3.z; m += w[15] * a3.w;
}

template<bool GATH>
__global__ __launch_bounds__(256, 8) void aggregate_kernel(
    const unsigned short* __restrict__ h16, const float* __restrict__ eaG,
    const int* __restrict__ perm, const int* __restrict__ src_perm,
    const int* __restrict__ row_start,
    const float* __restrict__ We, const float* __restrict__ be,
    float* __restrict__ t, int Nn)
{
    int tid = threadIdx.x;
    int lane = tid & 63;
    int c = lane * 2;
    v2f w[16];
#pragma unroll
    for (int k = 0; k < 16; ++k) w[k] = *(const v2f*)&We[k * HID + c];
    v2f bj = *(const v2f*)&be[c];
    int node = blockIdx.x * 4 + (tid >> 6);
    if (node >= Nn) return;
    const unsigned* __restrict__ hw = (const unsigned*)h16 + lane;  // bf16 ch-pair per lane
    v2f acc = unpack2(hw[(unsigned)node << 6]);
    int p0 = __builtin_amdgcn_readfirstlane(row_start[node]);
    int p1 = __builtin_amdgcn_readfirstlane(row_start[node + 1]);
    int p = p0;
    int s0 = 0, s1 = 0, s2 = 0, s3 = 0;
    if (p + 4 <= p1) { s0 = src_perm[p]; s1 = src_perm[p + 1]; s2 = src_perm[p + 2]; s3 = src_perm[p + 3]; }
    while (p + 4 <= p1) {
        int np = p + 4;
        int t0 = 0, t1 = 0, t2 = 0, t3 = 0;
        if (np + 4 <= p1) { t0 = src_perm[np]; t1 = src_perm[np + 1]; t2 = src_perm[np + 2]; t3 = src_perm[np + 3]; }
        // lane-varying h gather (one dword per lane per edge)
        unsigned hu0 = hw[(unsigned)s0 << 6];
        unsigned hu1 = hw[(unsigned)s1 << 6];
        unsigned hu2 = hw[(unsigned)s2 << 6];
        unsigned hu3 = hw[(unsigned)s3 << 6];
        // wave-uniform fp32 ea rows -> scalar pipe (no unpack)
        int q0, q1, q2, q3;
        if (GATH) { q0 = p; q1 = p + 1; q2 = p + 2; q3 = p + 3; }
        else      { q0 = perm[p]; q1 = perm[p + 1]; q2 = perm[p + 2]; q3 = perm[p + 3]; }
        const v4f* e0 = (const v4f*)(eaG + (size_t)(unsigned)q0 * EDIM);
        const v4f* e1 = (const v4f*)(eaG + (size_t)(unsigned)q1 * EDIM);
        const v4f* e2 = (const v4f*)(eaG + (size_t)(unsigned)q2 * EDIM);
        const v4f* e3 = (const v4f*)(eaG + (size_t)(unsigned)q3 * EDIM);
        v4f a00 = e0[0], a01 = e0[1], a02 = e0[2], a03 = e0[3];
        v4f a10 = e1[0], a11 = e1[1], a12 = e1[2], a13 = e1[3];
        v4f a20 = e2[0], a21 = e2[1], a22 = e2[2], a23 = e2[3];
        v4f a30 = e3[0], a31 = e3[1], a32 = e3[2], a33 = e3[3];
        v2f m0 = bj + unpack2(hu0), m1 = bj + unpack2(hu1);
        v2f m2 = bj + unpack2(hu2), m3 = bj + unpack2(hu3);
        matvp(a00, a01, a02, a03, w, m0);
        matvp(a10, a11, a12, a13, w, m1);
        matvp(a20, a21, a22, a23, w, m2);
        matvp(a30, a31, a32, a33, w, m3);
        acc += vmax0(m0) + vmax0(m1) + vmax0(m2) + vmax0(m3);
        p = np;
        s0 = t0; s1 = t1; s2 = t2; s3 = t3;
    }
    for (; p < p1; ++p) {
        int s = src_perm[p];
        int q = GATH ? p : perm[p];
        const v4f* e0 = (const v4f*)(eaG + (size_t)(unsigned)q * EDIM);
        v4f a0 = e0[0], a1 = e0[1], a2 = e0[2], a3 = e0[3];
        v2f m0 = bj + unpack2(hw[(unsigned)s << 6]);
        matvp(a0, a1, a2, a3, w, m0);
        acc += vmax0(m0);
    }
    *(v2f*)(t + ((unsigned)node << 7) + c) = acc;
}

// ================= split-bf16 MFMA GEMM =================
#define LPAD 40

template<int K, bool PRE_BN, bool POST_STATS, bool OUT_BF16>
__global__ __launch_bounds__(256) void gemm_mfma(
    const float* __restrict__ A, const unsigned short* __restrict__ Wh,
    const unsigned short* __restrict__ Wl, const float* __restrict__ bias,
    const float* __restrict__ preStats, const float* __restrict__ preG, const float* __restrict__ preB,
    void* __restrict__ Cout, float* __restrict__ postStats, int Nrows, float invN)
{
    __shared__ __align__(16) unsigned short Ah[128 * LPAD], Al[128 * LPAD];
    __shared__ __align__(16) unsigned short Bh[128 * LPAD], Bl[128 * LPAD];
    __shared__ float sc[PRE_BN ? K : 1], sb[PRE_BN ? K : 1];
    int tid = threadIdx.x;
    int rbase = blockIdx.x * 128;
    if (PRE_BN) {
        if (tid < K) {
            float mean = preStats[tid] * invN;
            float var = preStats[K + tid] * invN - mean * mean;
            float rstd = rsqrtf(var + 1e-5f);
            float g = preG[tid];
            sc[tid] = rstd * g;
            sb[tid] = preB[tid] - mean * rstd * g;
        }
        __syncthreads();
    }
    int w = tid >> 6, nl = tid & 15, q = (tid >> 4) & 3;
    f4v acc[2][8];
#pragma unroll
    for (int mt = 0; mt < 2; ++mt)
#pragma unroll
        for (int nt = 0; nt < 8; ++nt)
#pragma unroll
            for (int r = 0; r < 4; ++r) acc[mt][nt][r] = 0.f;

    for (int ks = 0; ks < K / 32; ++ks) {
        int k0 = ks * 32;
        if (ks) __syncthreads();
#pragma unroll
        for (int i = 0; i < 4; ++i) {
            int cidx = tid + i * 256;
            int m = cidx >> 3, k4 = (cidx & 7) * 4;
            int gr = rbase + m;
            float4 v = make_float4(0.f, 0.f, 0.f, 0.f);
            if (gr < Nrows) v = *(const float4*)&A[(size_t)gr * K + k0 + k4];
            if (PRE_BN) {
                v.x = fmaxf(v.x * sc[k0 + k4]     + sb[k0 + k4],     0.f);
                v.y = fmaxf(v.y * sc[k0 + k4 + 1] + sb[k0 + k4 + 1], 0.f);
                v.z = fmaxf(v.z * sc[k0 + k4 + 2] + sb[k0 + k4 + 2], 0.f);
                v.w = fmaxf(v.w * sc[k0 + k4 + 3] + sb[k0 + k4 + 3], 0.f);
            }
            unsigned short h0, l0, h1, l1, h2, l2, h3, l3;
            split_bf16(v.x, h0, l0); split_bf16(v.y, h1, l1);
            split_bf16(v.z, h2, l2); split_bf16(v.w, h3, l3);
            uint2 hp, lp;
            hp.x = (unsigned)h0 | ((unsigned)h1 << 16); hp.y = (unsigned)h2 | ((unsigned)h3 << 16);
            lp.x = (unsigned)l0 | ((unsigned)l1 << 16); lp.y = (unsigned)l2 | ((unsigned)l3 << 16);
            *(uint2*)&Ah[m * LPAD + k4] = hp;
            *(uint2*)&Al[m * LPAD + k4] = lp;
        }
#pragma unroll
        for (int i = 0; i < 2; ++i) {
            int g = tid + i * 256;
            int n = g >> 2, kq = (g & 3) * 8;
            uint4 hv = *(const uint4*)&Wh[(size_t)n * K + k0 + kq];
            uint4 lv = *(const uint4*)&Wl[(size_t)n * K + k0 + kq];
            *(uint4*)&Bh[n * LPAD + kq] = hv;
            *(uint4*)&Bl[n * LPAD + kq] = lv;
        }
        __syncthreads();
        s8v ah0 = *(const s8v*)&Ah[(w * 32 + nl) * LPAD + q * 8];
        s8v ah1 = *(const s8v*)&Ah[(w * 32 + 16 + nl) * LPAD + q * 8];
        s8v al0 = *(const s8v*)&Al[(w * 32 + nl) * LPAD + q * 8];
        s8v al1 = *(const s8v*)&Al[(w * 32 + 16 + nl) * LPAD + q * 8];
#pragma unroll
        for (int nt = 0; nt < 8; ++nt) {
            s8v bh = *(const s8v*)&Bh[(nt * 16 + nl) * LPAD + q * 8];
            s8v bl = *(const s8v*)&Bl[(nt * 16 + nl) * LPAD + q * 8];
            acc[0][nt] = MFMA_BF16(ah0, bh, acc[0][nt]);
            acc[0][nt] = MFMA_BF16(ah0, bl, acc[0][nt]);
            acc[0][nt] = MFMA_BF16(al0, bh, acc[0][nt]);
            acc[1][nt] = MFMA_BF16(ah1, bh, acc[1][nt]);
            acc[1][nt] = MFMA_BF16(ah1, bl, acc[1][nt]);
            acc[1][nt] = MFMA_BF16(al1, bh, acc[1][nt]);
        }
    }
    __syncthreads();

    float* Cf = (float*)Cout;
    unsigned short* Ch = (unsigned short*)Cout;
    float* redS = (float*)Ah;
    float* redQ = (float*)Al;
#pragma unroll
    for (int nt = 0; nt < 8; ++nt) {
        int col = nt * 16 + nl;
        float bcol = bias[col];
        float sv = 0.f, qv = 0.f;
#pragma unroll
        for (int mt = 0; mt < 2; ++mt) {
#pragma unroll
            for (int r = 0; r < 4; ++r) {
                int grow = rbase + w * 32 + mt * 16 + q * 4 + r;
                if (grow < Nrows) {
                    float o = acc[mt][nt][r] + bcol;
                    if (OUT_BF16) Ch[(size_t)grow * HID + col] = bf16_rne(o);
                    else          Cf[(size_t)grow * HID + col] = o;
                    if (POST_STATS) { sv += o; qv += o * o; }
                }
            }
        }
        if (POST_STATS) {
            sv += __shfl_down(sv, 32, 64); sv += __shfl_down(sv, 16, 64);
            qv += __shfl_down(qv, 32, 64); qv += __shfl_down(qv, 16, 64);
            if ((tid & 63) < 16) { redS[w * 128 + col] = sv; redQ[w * 128 + col] = qv; }
        }
    }
    if (POST_STATS) {
        __syncthreads();
        if (tid < 128) {
            float S = redS[tid] + redS[128 + tid] + redS[256 + tid] + redS[384 + tid];
            float Q = redQ[tid] + redQ[128 + tid] + redQ[256 + tid] + redQ[384 + tid];
            atomicAdd(&postStats[tid], S);
            atomicAdd(&postStats[128 + tid], Q);
        }
    }
}

// ======== fused BN apply + ReLU + pool; h stored as packed bf16 (pool uses exact fp32) ========
__global__ void bn_apply_pool(const float* __restrict__ X, unsigned short* __restrict__ h16,
                              const float* __restrict__ stats, const float* __restrict__ g,
                              const float* __restrict__ b, const int* __restrict__ starts,
                              float* __restrict__ z, int l, float invN)
{
    int gph = blockIdx.x;
    int tid = threadIdx.x;
    int ch4 = (tid & 31) * 4, wk = tid >> 5;   // 16 walkers x 32 lanes(float4)
    float sc[4], sh[4];
#pragma unroll
    for (int u = 0; u < 4; ++u) {
        int j = ch4 + u;
        float mean = stats[j] * invN;
        float var = stats[128 + j] * invN - mean * mean;
        float rstd = rsqrtf(var + 1e-5f);
        float gg = g[j];
        sc[u] = rstd * gg;
        sh[u] = b[j] - mean * rstd * gg;
    }
    int s = starts[gph], e = starts[gph + 1];
    float4 sum = make_float4(0.f, 0.f, 0.f, 0.f);
    float4 mx = make_float4(0.f, 0.f, 0.f, 0.f);
    unsigned* hv32 = (unsigned*)h16;
    for (int n = s + wk; n < e; n += 16) {
        float4 v = *(const float4*)&X[(size_t)n * HID + ch4];
        v.x = fmaxf(v.x * sc[0] + sh[0], 0.f);
        v.y = fmaxf(v.y * sc[1] + sh[1], 0.f);
        v.z = fmaxf(v.z * sc[2] + sh[2], 0.f);
        v.w = fmaxf(v.w * sc[3] + sh[3], 0.f);
        uint2 pk;
        pk.x = pack2(v.x, v.y);
        pk.y = pack2(v.z, v.w);
        *(uint2*)&hv32[(size_t)n * 64 + (ch4 >> 1)] = pk;
        sum.x += v.x; sum.y += v.y; sum.z += v.z; sum.w += v.w;
        mx.x = fmaxf(mx.x, v.x); mx.y = fmaxf(mx.y, v.y);
        mx.z = fmaxf(mx.z, v.z); mx.w = fmaxf(mx.w, v.w);
    }
    __shared__ float ls[16 * 128], lm[16 * 128];
    *(float4*)&ls[wk * 128 + ch4] = sum;
    *(float4*)&lm[wk * 128 + ch4] = mx;
    __syncthreads();
    if (tid < 128) {
        float S = 0.f, M = 0.f;
#pragma unroll
        for (int k = 0; k < 16; ++k) {
            S += ls[k * 128 + tid];
            M = fmaxf(M, lm[k * 128 + tid]);
        }
        float cnt = (float)(e - s);
        z[(size_t)gph * 768 + l * 128 + tid] = S / fmaxf(cnt, 1.f);
        z[(size_t)gph * 768 + 384 + l * 128 + tid] = M;
    }
}

// ================= segment boundaries (batch sorted) =================
__global__ void starts_kernel(const int* __restrict__ batch, int* __restrict__ starts,
                              int Nn, int Gn)
{
    int g = blockIdx.x * blockDim.x + threadIdx.x;
    if (g > Gn) return;
    int lo = 0, hi = Nn;
    while (lo < hi) { int mid = (lo + hi) >> 1; if (batch[mid] < g) lo = mid + 1; else hi = mid; }
    starts[g] = lo;
}

// ================= head =================
__global__ void head_gemm1(const float* __restrict__ z, const float* __restrict__ W,
                           const float* __restrict__ bias, float* __restrict__ zr,
                           float* __restrict__ msums)
{
    __shared__ __align__(16) float zl[768];
    int g = blockIdx.x, j = threadIdx.x;
    for (int i = j; i < 768; i += 128) zl[i] = z[(size_t)g * 768 + i];
    __syncthreads();
    float acc = bias[j];
    for (int k = 0; k < 768; k += 4) {
        float4 a4 = *(const float4*)&zl[k];
        acc += a4.x * W[k * 128 + j] + a4.y * W[(k + 1) * 128 + j]
             + a4.z * W[(k + 2) * 128 + j] + a4.w * W[(k + 3) * 128 + j];
    }
    zr[(size_t)g * 128 + j] = acc;
    atomicAdd(&msums[j], acc);
    atomicAdd(&msums[128 + j], acc * acc);
}

__global__ void head_final(const float* __restrict__ zr, const float* __restrict__ msums,
                           const float* __restrict__ hg, const float* __restrict__ hb,
                           const float* __restrict__ W2, const float* __restrict__ b2,
                           float* __restrict__ out, float invG)
{
    int g = blockIdx.x, j = threadIdx.x;
    float mean = msums[j] * invG;
    float var = msums[128 + j] * invG - mean * mean;
    float rstd = rsqrtf(var + 1e-5f);
    float v = zr[(size_t)g * 128 + j];
    v = (v - mean) * rstd * hg[j] + hb[j];
    v = fmaxf(v, 0.f);
    float p = v * W2[j];
#pragma unroll
    for (int off = 32; off > 0; off >>= 1) p += __shfl_down(p, off, 64);
    __shared__ float partial[2];
    if ((j & 63) == 0) partial[j >> 6] = p;
    __syncthreads();
    if (j == 0) out[g] = partial[0] + partial[1] + b2[0];
}

extern "C" void kernel_launch(void* const* d_in, const int* in_sizes, int n_in,
                              void* d_out, int out_size, void* d_ws, size_t ws_size,
                              hipStream_t stream)
{
    const float* x         = (const float*)d_in[0];
    const float* edge_attr = (const float*)d_in[1];
    const int*   src       = (const int*)d_in[2];
    const int*   dst       = (const int*)d_in[3];
    const int*   batch     = (const int*)d_in[4];
    const float* Wp        = (const float*)d_in[5];
    const float* bp        = (const float*)d_in[6];
    const float* conv_We   = (const float*)d_in[7];
    const float* conv_be   = (const float*)d_in[8];
    const float* conv_W1   = (const float*)d_in[9];
    const float* conv_b1   = (const float*)d_in[10];
    const float* conv_g1   = (const float*)d_in[11];
    const float* conv_bt1  = (const float*)d_in[12];
    const float* conv_W2   = (const float*)d_in[13];
    const float* conv_b2   = (const float*)d_in[14];
    const float* bn_g      = (const float*)d_in[15];
    const float* bn_b      = (const float*)d_in[16];
    const float* head_W1   = (const float*)d_in[17];
    const float* head_b1   = (const float*)d_in[18];
    const float* head_g    = (const float*)d_in[19];
    const float* head_bt   = (const float*)d_in[20];
    const float* head_W2   = (const float*)d_in[21];
    const float* head_b2   = (const float*)d_in[22];

    const int N = in_sizes[4];            // 50000
    const int E = in_sizes[2];            // 800000
    const int G = out_size;               // 256
    const int L = 3;

    // ---- workspace layout ----
    float* t        = (float*)d_ws;                  // N*128 fp32
    unsigned short* h16 = (unsigned short*)(t + (size_t)N * HID);  // N*128 bf16
    float* z        = (float*)(h16 + (size_t)N * HID);             // G*768
    float* zr       = z + (size_t)G * 768;           // G*128
    float* statsAll = zr + (size_t)G * HID;          // 7*256
    int*   deg      = (int*)(statsAll + 7 * 256);    // N
    int*   starts   = deg + N;                       // G+1
    int*   row_start= starts + (G + 1);              // N+1
    int*   cursor   = row_start + (N + 1);           // N
    int*   bsum     = cursor + N;                    // 256
    int*   src_perm = bsum + 256;                    // E
    int*   perm     = src_perm + E;                  // E (fallback only)
    unsigned short* wt = (unsigned short*)(perm + E);  // 212992 ushorts
    size_t base_end = (size_t)((char*)(wt + 212992) - (char*)d_ws);
    size_t ea_off = (base_end + 15) & ~(size_t)15;
    bool gath = (ea_off + (size_t)E * EDIM * sizeof(float)) <= ws_size;
    float* ea_perm = (float*)((char*)d_ws + ea_off);
    float* msums = statsAll + 6 * 256;

    (void)n_in;

    const float invN = 1.0f / (float)N;
    const float invG = 1.0f / (float)G;
    const int nb = (N + 255) / 256;
    const int gemmBlocks = (N + 127) / 128;

    // ---- CSR build + weight prep ----
    (void)hipMemsetAsync(statsAll, 0, 7 * 256 * sizeof(float) + (size_t)N * sizeof(int), stream);
    hist_kernel<<<(E + 255) / 256, 256, 0, stream>>>(dst, deg, E);
    block_sum_kernel<<<nb, 256, 0, stream>>>(deg, bsum, N);
    bsum_scan_kernel<<<1, 256, 0, stream>>>(bsum, nb, &row_start[N]);
    block_scan_kernel<<<nb, 256, 0, stream>>>(deg, bsum, row_start, cursor, N);
    if (gath)
        scatter_kernel<true><<<(E + 255) / 256, 256, 0, stream>>>(
            src, dst, cursor, perm, src_perm, edge_attr, ea_perm, E);
    else
        scatter_kernel<false><<<(E + 255) / 256, 256, 0, stream>>>(
            src, dst, cursor, perm, src_perm, edge_attr, ea_perm, E);
    starts_kernel<<<1, 512, 0, stream>>>(batch, starts, N, G);
    prep_weights<<<(8192 + 6 * 16384 + 255) / 256, 256, 0, stream>>>(Wp, conv_W1, conv_W2, wt);

    const unsigned short* Wp_hi = wt;
    const unsigned short* Wp_lo = wt + 8192;

    // h16 = bf16(x @ Wp + bp)
    gemm_mfma<64, false, false, true><<<gemmBlocks, 256, 0, stream>>>(
        x, Wp_hi, Wp_lo, bp, nullptr, nullptr, nullptr, h16, nullptr, N, invN);

    for (int l = 0; l < L; ++l) {
        float* sI = statsAll + l * 512;
        float* sO = sI + 256;
        const unsigned short* W1hi = wt + 16384 + (size_t)(2 * l) * 32768;
        const unsigned short* W1lo = W1hi + 16384;
        const unsigned short* W2hi = wt + 16384 + (size_t)(2 * l + 1) * 32768;
        const unsigned short* W2lo = W2hi + 16384;
        if (gath)
            aggregate_kernel<true><<<(N + 3) / 4, 256, 0, stream>>>(
                h16, ea_perm, perm, src_perm, row_start,
                conv_We + (size_t)l * EDIM * HID, conv_be + l * HID, t, N);
        else
            aggregate_kernel<false><<<(N + 3) / 4, 256, 0, stream>>>(
                h16, edge_attr, perm, src_perm, row_start,
                conv_We + (size_t)l * EDIM * HID, conv_be + l * HID, t, N);
        gemm_mfma<128, false, true, false><<<gemmBlocks, 256, 0, stream>>>(
            t, W1hi, W1lo, conv_b1 + l * HID,
            nullptr, nullptr, nullptr, t, sI, N, invN);
        gemm_mfma<128, true, true, false><<<gemmBlocks, 256, 0, stream>>>(
            t, W2hi, W2lo, conv_b2 + l * HID,
            sI, conv_g1 + l * HID, conv_bt1 + l * HID, t, sO, N, invN);
        bn_apply_pool<<<G, 512, 0, stream>>>(
            t, h16, sO, bn_g + l * HID, bn_b + l * HID, starts, z, l, invN);
    }

    head_gemm1<<<G, 128, 0, stream>>>(z, head_W1, head_b1, zr, msums);
    head_final<<<G, 128, 0, stream>>>(zr, msums, head_g, head_bt, head_W2, head_b2,
                                      (float*)d_out, invG);
}

// Round 12
// 684.505 us; speedup vs baseline: 1.1608x; 1.1608x over previous
//
#include <hip/hip_runtime.h>
#include <hip/hip_bf16.h>

#define HID 128
#define EDIM 16

typedef float v4f __attribute__((ext_vector_type(4)));
typedef float v2f __attribute__((ext_vector_type(2)));
typedef short s8v __attribute__((ext_vector_type(8)));   // 8 bf16 (4 VGPRs) MFMA frag
typedef float f4v __attribute__((ext_vector_type(4)));   // MFMA acc

#define MFMA_BF16(a, b, c) __builtin_amdgcn_mfma_f32_16x16x32_bf16((a), (b), (c), 0, 0, 0)

__device__ __forceinline__ unsigned short bf16_rne(float v)
{
    unsigned u = __builtin_bit_cast(unsigned, v);
    return (unsigned short)((u + 0x7fffu + ((u >> 16) & 1u)) >> 16);
}

__device__ __forceinline__ unsigned pack2(float lo, float hi)
{
    return (unsigned)bf16_rne(lo) | ((unsigned)bf16_rne(hi) << 16);
}

__device__ __forceinline__ float bflo(unsigned u) { return __builtin_bit_cast(float, u << 16); }
__device__ __forceinline__ float bfhi(unsigned u) { return __builtin_bit_cast(float, u & 0xffff0000u); }

__device__ __forceinline__ v2f unpack2(unsigned u)
{
    v2f r; r.x = bflo(u); r.y = bfhi(u); return r;
}

__device__ __forceinline__ void split_bf16(float v, unsigned short& h, unsigned short& l)
{
    unsigned u = __builtin_bit_cast(unsigned, v);
    unsigned hu = (u + 0x7fffu + ((u >> 16) & 1u)) >> 16;
    h = (unsigned short)hu;
    float hf = __builtin_bit_cast(float, hu << 16);
    l = bf16_rne(v - hf);
}

__device__ __forceinline__ v2f vmax0(v2f a)
{
    v2f r; r.x = fmaxf(a.x, 0.f); r.y = fmaxf(a.y, 0.f); return r;
}

// ================= CSR build =================
__global__ void hist_kernel(const int* __restrict__ dst, int* __restrict__ deg, int E)
{
    int e = blockIdx.x * 256 + threadIdx.x;
    if (e < E) atomicAdd(&deg[dst[e]], 1);
}

__global__ void block_sum_kernel(const int* __restrict__ deg, int* __restrict__ bsum, int Nn)
{
    int i = blockIdx.x * 256 + threadIdx.x;
    int v = (i < Nn) ? deg[i] : 0;
#pragma unroll
    for (int off = 32; off > 0; off >>= 1) v += __shfl_down(v, off, 64);
    __shared__ int ws[4];
    if ((threadIdx.x & 63) == 0) ws[threadIdx.x >> 6] = v;
    __syncthreads();
    if (threadIdx.x == 0) bsum[blockIdx.x] = ws[0] + ws[1] + ws[2] + ws[3];
}

__global__ void bsum_scan_kernel(int* bsum, int nb, int* total_out)
{
    __shared__ int sh[256];
    int tid = threadIdx.x;
    int v = (tid < nb) ? bsum[tid] : 0;
    sh[tid] = v;
    __syncthreads();
    for (int off = 1; off < 256; off <<= 1) {
        int tv = (tid >= off) ? sh[tid - off] : 0;
        __syncthreads();
        sh[tid] += tv;
        __syncthreads();
    }
    if (tid < nb) bsum[tid] = sh[tid] - v;
    if (tid == 255) *total_out = sh[255];
}

__global__ void block_scan_kernel(const int* __restrict__ deg, const int* __restrict__ bsum,
                                  int* __restrict__ row_start, int* __restrict__ cursor, int Nn)
{
    __shared__ int sh[256];
    int tid = threadIdx.x;
    int i = blockIdx.x * 256 + tid;
    int v = (i < Nn) ? deg[i] : 0;
    sh[tid] = v;
    __syncthreads();
    for (int off = 1; off < 256; off <<= 1) {
        int tv = (tid >= off) ? sh[tid - off] : 0;
        __syncthreads();
        sh[tid] += tv;
        __syncthreads();
    }
    if (i < Nn) {
        int excl = sh[tid] - v + bsum[blockIdx.x];
        row_start[i] = excl;
        cursor[i] = excl;
    }
}

// scatter + fused ea permute (fp32, PLAIN stores — L2 coalesces adjacent CSR rows;
// nt-stores regressed 77->166 us in R11 by forcing partial-line HBM writes)
template<bool COPY_EA>
__global__ void scatter_kernel(const int* __restrict__ src, const int* __restrict__ dst,
                               int* cursor, int* __restrict__ perm,
                               int* __restrict__ src_perm,
                               const float* __restrict__ ea, float* __restrict__ ea_perm,
                               int E)
{
    int e = blockIdx.x * 256 + threadIdx.x;
    if (e >= E) return;
    int pos = atomicAdd(&cursor[dst[e]], 1);
    src_perm[pos] = src[e];
    if (COPY_EA) {
        const v4f* s4 = (const v4f*)(ea + (size_t)e * EDIM);
        v4f a = s4[0], b = s4[1], c = s4[2], d = s4[3];
        v4f* dp = (v4f*)(ea_perm + (size_t)pos * EDIM);
        dp[0] = a; dp[1] = b; dp[2] = c; dp[3] = d;
    } else {
        perm[pos] = e;
    }
}

// ================= weight prep: fp32 [K,128] -> transposed split-bf16 [128,K] hi/lo =================
__global__ void prep_weights(const float* __restrict__ Wp, const float* __restrict__ W1,
                             const float* __restrict__ W2, unsigned short* __restrict__ out)
{
    int idx = blockIdx.x * 256 + threadIdx.x;
    if (idx < 8192) {
        int n = idx >> 6, k = idx & 63;
        unsigned short h, l;
        split_bf16(Wp[k * 128 + n], h, l);
        out[idx] = h;
        out[8192 + idx] = l;
    } else {
        int j = idx - 8192;
        if (j >= 6 * 16384) return;
        int m2 = j >> 14;
        int r = j & 16383;
        int n = r >> 7, k = r & 127;
        int l = m2 >> 1;
        const float* Wsrc = (m2 & 1) ? (W2 + l * 16384) : (W1 + l * 16384);
        unsigned short h, lo;
        split_bf16(Wsrc[k * 128 + n], h, lo);
        int base = 16384 + m2 * 32768;
        out[base + r] = h;
        out[base + 16384 + r] = lo;
    }
}

// ====== Node-centric aggregation: 1 wave/node, 2 ch/lane; fp32 ea via scalar pipe, bf16 h gather ======
__device__ __forceinline__ void matvp(const v4f& a0, const v4f& a1,
                                      const v4f& a2, const v4f& a3,
                                      const v2f* __restrict__ w, v2f& m)
{
    m += w[0] * a0.x;  m += w[1] * a0.y;  m += w[2] * a0.z;  m += w[3] * a0.w;
    m += w[4] * a1.x;  m += w[5] * a1.y;  m += w[6] * a1.z;  m += w[7] * a1.w;
    m += w[8] * a2.x;  m += w[9] * a2.y;  m += w[10] * a2.z; m += w[11] * a2.w;
    m += w[12] * a3.x; m += w[13] * a3.y; m += w[14] * a3.z; m += w[15] * a3.w;
}

template<bool GATH>
__global__ __launch_bounds__(256, 8) void aggregate_kernel(
    const unsigned short* __restrict__ h16, const float* __restrict__ eaG,
    const int* __restrict__ perm, const int* __restrict__ src_perm,
    const int* __restrict__ row_start,
    const float* __restrict__ We, const float* __restrict__ be,
    float* __restrict__ t, int Nn)
{
    int tid = threadIdx.x;
    int lane = tid & 63;
    int c = lane * 2;
    v2f w[16];
#pragma unroll
    for (int k = 0; k < 16; ++k) w[k] = *(const v2f*)&We[k * HID + c];
    v2f bj = *(const v2f*)&be[c];
    int node = blockIdx.x * 4 + (tid >> 6);
    if (node >= Nn) return;
    const unsigned* __restrict__ hw = (const unsigned*)h16 + lane;  // bf16 ch-pair per lane
    v2f acc = unpack2(hw[(unsigned)node << 6]);
    int p0 = __builtin_amdgcn_readfirstlane(row_start[node]);
    int p1 = __builtin_amdgcn_readfirstlane(row_start[node + 1]);
    int p = p0;
    int s0 = 0, s1 = 0, s2 = 0, s3 = 0;
    if (p + 4 <= p1) { s0 = src_perm[p]; s1 = src_perm[p + 1]; s2 = src_perm[p + 2]; s3 = src_perm[p + 3]; }
    while (p + 4 <= p1) {
        int np = p + 4;
        int t0 = 0, t1 = 0, t2 = 0, t3 = 0;
        if (np + 4 <= p1) { t0 = src_perm[np]; t1 = src_perm[np + 1]; t2 = src_perm[np + 2]; t3 = src_perm[np + 3]; }
        // lane-varying h gather (one dword per lane per edge)
        unsigned hu0 = hw[(unsigned)s0 << 6];
        unsigned hu1 = hw[(unsigned)s1 << 6];
        unsigned hu2 = hw[(unsigned)s2 << 6];
        unsigned hu3 = hw[(unsigned)s3 << 6];
        // wave-uniform fp32 ea rows -> scalar pipe (no unpack)
        int q0, q1, q2, q3;
        if (GATH) { q0 = p; q1 = p + 1; q2 = p + 2; q3 = p + 3; }
        else      { q0 = perm[p]; q1 = perm[p + 1]; q2 = perm[p + 2]; q3 = perm[p + 3]; }
        const v4f* e0 = (const v4f*)(eaG + (size_t)(unsigned)q0 * EDIM);
        const v4f* e1 = (const v4f*)(eaG + (size_t)(unsigned)q1 * EDIM);
        const v4f* e2 = (const v4f*)(eaG + (size_t)(unsigned)q2 * EDIM);
        const v4f* e3 = (const v4f*)(eaG + (size_t)(unsigned)q3 * EDIM);
        v4f a00 = e0[0], a01 = e0[1], a02 = e0[2], a03 = e0[3];
        v4f a10 = e1[0], a11 = e1[1], a12 = e1[2], a13 = e1[3];
        v4f a20 = e2[0], a21 = e2[1], a22 = e2[2], a23 = e2[3];
        v4f a30 = e3[0], a31 = e3[1], a32 = e3[2], a33 = e3[3];
        v2f m0 = bj + unpack2(hu0), m1 = bj + unpack2(hu1);
        v2f m2 = bj + unpack2(hu2), m3 = bj + unpack2(hu3);
        matvp(a00, a01, a02, a03, w, m0);
        matvp(a10, a11, a12, a13, w, m1);
        matvp(a20, a21, a22, a23, w, m2);
        matvp(a30, a31, a32, a33, w, m3);
        acc += vmax0(m0) + vmax0(m1) + vmax0(m2) + vmax0(m3);
        p = np;
        s0 = t0; s1 = t1; s2 = t2; s3 = t3;
    }
    for (; p < p1; ++p) {
        int s = src_perm[p];
        int q = GATH ? p : perm[p];
        const v4f* e0 = (const v4f*)(eaG + (size_t)(unsigned)q * EDIM);
        v4f a0 = e0[0], a1 = e0[1], a2 = e0[2], a3 = e0[3];
        v2f m0 = bj + unpack2(hw[(unsigned)s << 6]);
        matvp(a0, a1, a2, a3, w, m0);
        acc += vmax0(m0);
    }
    *(v2f*)(t + ((unsigned)node << 7) + c) = acc;
}

// ================= split-bf16 MFMA GEMM =================
#define LPAD 40

template<int K, bool PRE_BN, bool POST_STATS, bool OUT_BF16>
__global__ __launch_bounds__(256) void gemm_mfma(
    const float* __restrict__ A, const unsigned short* __restrict__ Wh,
    const unsigned short* __restrict__ Wl, const float* __restrict__ bias,
    const float* __restrict__ preStats, const float* __restrict__ preG, const float* __restrict__ preB,
    void* __restrict__ Cout, float* __restrict__ postStats, int Nrows, float invN)
{
    __shared__ __align__(16) unsigned short Ah[128 * LPAD], Al[128 * LPAD];
    __shared__ __align__(16) unsigned short Bh[128 * LPAD], Bl[128 * LPAD];
    __shared__ float sc[PRE_BN ? K : 1], sb[PRE_BN ? K : 1];
    int tid = threadIdx.x;
    int rbase = blockIdx.x * 128;
    if (PRE_BN) {
        if (tid < K) {
            float mean = preStats[tid] * invN;
            float var = preStats[K + tid] * invN - mean * mean;
            float rstd = rsqrtf(var + 1e-5f);
            float g = preG[tid];
            sc[tid] = rstd * g;
            sb[tid] = preB[tid] - mean * rstd * g;
        }
        __syncthreads();
    }
    int w = tid >> 6, nl = tid & 15, q = (tid >> 4) & 3;
    f4v acc[2][8];
#pragma unroll
    for (int mt = 0; mt < 2; ++mt)
#pragma unroll
        for (int nt = 0; nt < 8; ++nt)
#pragma unroll
            for (int r = 0; r < 4; ++r) acc[mt][nt][r] = 0.f;

    for (int ks = 0; ks < K / 32; ++ks) {
        int k0 = ks * 32;
        if (ks) __syncthreads();
#pragma unroll
        for (int i = 0; i < 4; ++i) {
            int cidx = tid + i * 256;
            int m = cidx >> 3, k4 = (cidx & 7) * 4;
            int gr = rbase + m;
            float4 v = make_float4(0.f, 0.f, 0.f, 0.f);
            if (gr < Nrows) v = *(const float4*)&A[(size_t)gr * K + k0 + k4];
            if (PRE_BN) {
                v.x = fmaxf(v.x * sc[k0 + k4]     + sb[k0 + k4],     0.f);
                v.y = fmaxf(v.y * sc[k0 + k4 + 1] + sb[k0 + k4 + 1], 0.f);
                v.z = fmaxf(v.z * sc[k0 + k4 + 2] + sb[k0 + k4 + 2], 0.f);
                v.w = fmaxf(v.w * sc[k0 + k4 + 3] + sb[k0 + k4 + 3], 0.f);
            }
            unsigned short h0, l0, h1, l1, h2, l2, h3, l3;
            split_bf16(v.x, h0, l0); split_bf16(v.y, h1, l1);
            split_bf16(v.z, h2, l2); split_bf16(v.w, h3, l3);
            uint2 hp, lp;
            hp.x = (unsigned)h0 | ((unsigned)h1 << 16); hp.y = (unsigned)h2 | ((unsigned)h3 << 16);
            lp.x = (unsigned)l0 | ((unsigned)l1 << 16); lp.y = (unsigned)l2 | ((unsigned)l3 << 16);
            *(uint2*)&Ah[m * LPAD + k4] = hp;
            *(uint2*)&Al[m * LPAD + k4] = lp;
        }
#pragma unroll
        for (int i = 0; i < 2; ++i) {
            int g = tid + i * 256;
            int n = g >> 2, kq = (g & 3) * 8;
            uint4 hv = *(const uint4*)&Wh[(size_t)n * K + k0 + kq];
            uint4 lv = *(const uint4*)&Wl[(size_t)n * K + k0 + kq];
            *(uint4*)&Bh[n * LPAD + kq] = hv;
            *(uint4*)&Bl[n * LPAD + kq] = lv;
        }
        __syncthreads();
        s8v ah0 = *(const s8v*)&Ah[(w * 32 + nl) * LPAD + q * 8];
        s8v ah1 = *(const s8v*)&Ah[(w * 32 + 16 + nl) * LPAD + q * 8];
        s8v al0 = *(const s8v*)&Al[(w * 32 + nl) * LPAD + q * 8];
        s8v al1 = *(const s8v*)&Al[(w * 32 + 16 + nl) * LPAD + q * 8];
#pragma unroll
        for (int nt = 0; nt < 8; ++nt) {
            s8v bh = *(const s8v*)&Bh[(nt * 16 + nl) * LPAD + q * 8];
            s8v bl = *(const s8v*)&Bl[(nt * 16 + nl) * LPAD + q * 8];
            acc[0][nt] = MFMA_BF16(ah0, bh, acc[0][nt]);
            acc[0][nt] = MFMA_BF16(ah0, bl, acc[0][nt]);
            acc[0][nt] = MFMA_BF16(al0, bh, acc[0][nt]);
            acc[1][nt] = MFMA_BF16(ah1, bh, acc[1][nt]);
            acc[1][nt] = MFMA_BF16(ah1, bl, acc[1][nt]);
            acc[1][nt] = MFMA_BF16(al1, bh, acc[1][nt]);
        }
    }
    __syncthreads();

    float* Cf = (float*)Cout;
    unsigned short* Ch = (unsigned short*)Cout;
    float* redS = (float*)Ah;
    float* redQ = (float*)Al;
#pragma unroll
    for (int nt = 0; nt < 8; ++nt) {
        int col = nt * 16 + nl;
        float bcol = bias[col];
        float sv = 0.f, qv = 0.f;
#pragma unroll
        for (int mt = 0; mt < 2; ++mt) {
#pragma unroll
            for (int r = 0; r < 4; ++r) {
                int grow = rbase + w * 32 + mt * 16 + q * 4 + r;
                if (grow < Nrows) {
                    float o = acc[mt][nt][r] + bcol;
                    if (OUT_BF16) Ch[(size_t)grow * HID + col] = bf16_rne(o);
                    else          Cf[(size_t)grow * HID + col] = o;
                    if (POST_STATS) { sv += o; qv += o * o; }
                }
            }
        }
        if (POST_STATS) {
            sv += __shfl_down(sv, 32, 64); sv += __shfl_down(sv, 16, 64);
            qv += __shfl_down(qv, 32, 64); qv += __shfl_down(qv, 16, 64);
            if ((tid & 63) < 16) { redS[w * 128 + col] = sv; redQ[w * 128 + col] = qv; }
        }
    }
    if (POST_STATS) {
        __syncthreads();
        if (tid < 128) {
            float S = redS[tid] + redS[128 + tid] + redS[256 + tid] + redS[384 + tid];
            float Q = redQ[tid] + redQ[128 + tid] + redQ[256 + tid] + redQ[384 + tid];
            atomicAdd(&postStats[tid], S);
            atomicAdd(&postStats[128 + tid], Q);
        }
    }
}

// ======== fused BN apply + ReLU + pool; h stored as packed bf16 (pool uses exact fp32) ========
__global__ void bn_apply_pool(const float* __restrict__ X, unsigned short* __restrict__ h16,
                              const float* __restrict__ stats, const float* __restrict__ g,
                              const float* __restrict__ b, const int* __restrict__ starts,
                              float* __restrict__ z, int l, float invN)
{
    int gph = blockIdx.x;
    int tid = threadIdx.x;
    int ch4 = (tid & 31) * 4, wk = tid >> 5;   // 16 walkers x 32 lanes(float4)
    float sc[4], sh[4];
#pragma unroll
    for (int u = 0; u < 4; ++u) {
        int j = ch4 + u;
        float mean = stats[j] * invN;
        float var = stats[128 + j] * invN - mean * mean;
        float rstd = rsqrtf(var + 1e-5f);
        float gg = g[j];
        sc[u] = rstd * gg;
        sh[u] = b[j] - mean * rstd * gg;
    }
    int s = starts[gph], e = starts[gph + 1];
    float4 sum = make_float4(0.f, 0.f, 0.f, 0.f);
    float4 mx = make_float4(0.f, 0.f, 0.f, 0.f);
    unsigned* hv32 = (unsigned*)h16;
    for (int n = s + wk; n < e; n += 16) {
        float4 v = *(const float4*)&X[(size_t)n * HID + ch4];
        v.x = fmaxf(v.x * sc[0] + sh[0], 0.f);
        v.y = fmaxf(v.y * sc[1] + sh[1], 0.f);
        v.z = fmaxf(v.z * sc[2] + sh[2], 0.f);
        v.w = fmaxf(v.w * sc[3] + sh[3], 0.f);
        uint2 pk;
        pk.x = pack2(v.x, v.y);
        pk.y = pack2(v.z, v.w);
        *(uint2*)&hv32[(size_t)n * 64 + (ch4 >> 1)] = pk;
        sum.x += v.x; sum.y += v.y; sum.z += v.z; sum.w += v.w;
        mx.x = fmaxf(mx.x, v.x); mx.y = fmaxf(mx.y, v.y);
        mx.z = fmaxf(mx.z, v.z); mx.w = fmaxf(mx.w, v.w);
    }
    __shared__ float ls[16 * 128], lm[16 * 128];
    *(float4*)&ls[wk * 128 + ch4] = sum;
    *(float4*)&lm[wk * 128 + ch4] = mx;
    __syncthreads();
    if (tid < 128) {
        float S = 0.f, M = 0.f;
#pragma unroll
        for (int k = 0; k < 16; ++k) {
            S += ls[k * 128 + tid];
            M = fmaxf(M, lm[k * 128 + tid]);
        }
        float cnt = (float)(e - s);
        z[(size_t)gph * 768 + l * 128 + tid] = S / fmaxf(cnt, 1.f);
        z[(size_t)gph * 768 + 384 + l * 128 + tid] = M;
    }
}

// ================= segment boundaries (batch sorted) =================
__global__ void starts_kernel(const int* __restrict__ batch, int* __restrict__ starts,
                              int Nn, int Gn)
{
    int g = blockIdx.x * blockDim.x + threadIdx.x;
    if (g > Gn) return;
    int lo = 0, hi = Nn;
    while (lo < hi) { int mid = (lo + hi) >> 1; if (batch[mid] < g) lo = mid + 1; else hi = mid; }
    starts[g] = lo;
}

// ================= head =================
__global__ void head_gemm1(const float* __restrict__ z, const float* __restrict__ W,
                           const float* __restrict__ bias, float* __restrict__ zr,
                           float* __restrict__ msums)
{
    __shared__ __align__(16) float zl[768];
    int g = blockIdx.x, j = threadIdx.x;
    for (int i = j; i < 768; i += 128) zl[i] = z[(size_t)g * 768 + i];
    __syncthreads();
    float acc = bias[j];
    for (int k = 0; k < 768; k += 4) {
        float4 a4 = *(const float4*)&zl[k];
        acc += a4.x * W[k * 128 + j] + a4.y * W[(k + 1) * 128 + j]
             + a4.z * W[(k + 2) * 128 + j] + a4.w * W[(k + 3) * 128 + j];
    }
    zr[(size_t)g * 128 + j] = acc;
    atomicAdd(&msums[j], acc);
    atomicAdd(&msums[128 + j], acc * acc);
}

__global__ void head_final(const float* __restrict__ zr, const float* __restrict__ msums,
                           const float* __restrict__ hg, const float* __restrict__ hb,
                           const float* __restrict__ W2, const float* __restrict__ b2,
                           float* __restrict__ out, float invG)
{
    int g = blockIdx.x, j = threadIdx.x;
    float mean = msums[j] * invG;
    float var = msums[128 + j] * invG - mean * mean;
    float rstd = rsqrtf(var + 1e-5f);
    float v = zr[(size_t)g * 128 + j];
    v = (v - mean) * rstd * hg[j] + hb[j];
    v = fmaxf(v, 0.f);
    float p = v * W2[j];
#pragma unroll
    for (int off = 32; off > 0; off >>= 1) p += __shfl_down(p, off, 64);
    __shared__ float partial[2];
    if ((j & 63) == 0) partial[j >> 6] = p;
    __syncthreads();
    if (j == 0) out[g] = partial[0] + partial[1] + b2[0];
}

extern "C" void kernel_launch(void* const* d_in, const int* in_sizes, int n_in,
                              void* d_out, int out_size, void* d_ws, size_t ws_size,
                              hipStream_t stream)
{
    const float* x         = (const float*)d_in[0];
    const float* edge_attr = (const float*)d_in[1];
    const int*   src       = (const int*)d_in[2];
    const int*   dst       = (const int*)d_in[3];
    const int*   batch     = (const int*)d_in[4];
    const float* Wp        = (const float*)d_in[5];
    const float* bp        = (const float*)d_in[6];
    const float* conv_We   = (const float*)d_in[7];
    const float* conv_be   = (const float*)d_in[8];
    const float* conv_W1   = (const float*)d_in[9];
    const float* conv_b1   = (const float*)d_in[10];
    const float* conv_g1   = (const float*)d_in[11];
    const float* conv_bt1  = (const float*)d_in[12];
    const float* conv_W2   = (const float*)d_in[13];
    const float* conv_b2   = (const float*)d_in[14];
    const float* bn_g      = (const float*)d_in[15];
    const float* bn_b      = (const float*)d_in[16];
    const float* head_W1   = (const float*)d_in[17];
    const float* head_b1   = (const float*)d_in[18];
    const float* head_g    = (const float*)d_in[19];
    const float* head_bt   = (const float*)d_in[20];
    const float* head_W2   = (const float*)d_in[21];
    const float* head_b2   = (const float*)d_in[22];

    const int N = in_sizes[4];            // 50000
    const int E = in_sizes[2];            // 800000
    const int G = out_size;               // 256
    const int L = 3;

    // ---- workspace layout ----
    float* t        = (float*)d_ws;                  // N*128 fp32
    unsigned short* h16 = (unsigned short*)(t + (size_t)N * HID);  // N*128 bf16
    float* z        = (float*)(h16 + (size_t)N * HID);             // G*768
    float* zr       = z + (size_t)G * 768;           // G*128
    float* statsAll = zr + (size_t)G * HID;          // 7*256
    int*   deg      = (int*)(statsAll + 7 * 256);    // N
    int*   starts   = deg + N;                       // G+1
    int*   row_start= starts + (G + 1);              // N+1
    int*   cursor   = row_start + (N + 1);           // N
    int*   bsum     = cursor + N;                    // 256
    int*   src_perm = bsum + 256;                    // E
    int*   perm     = src_perm + E;                  // E (fallback only)
    unsigned short* wt = (unsigned short*)(perm + E);  // 212992 ushorts
    size_t base_end = (size_t)((char*)(wt + 212992) - (char*)d_ws);
    size_t ea_off = (base_end + 15) & ~(size_t)15;
    bool gath = (ea_off + (size_t)E * EDIM * sizeof(float)) <= ws_size;
    float* ea_perm = (float*)((char*)d_ws + ea_off);
    float* msums = statsAll + 6 * 256;

    (void)n_in;

    const float invN = 1.0f / (float)N;
    const float invG = 1.0f / (float)G;
    const int nb = (N + 255) / 256;
    const int gemmBlocks = (N + 127) / 128;

    // ---- CSR build + weight prep ----
    (void)hipMemsetAsync(statsAll, 0, 7 * 256 * sizeof(float) + (size_t)N * sizeof(int), stream);
    hist_kernel<<<(E + 255) / 256, 256, 0, stream>>>(dst, deg, E);
    block_sum_kernel<<<nb, 256, 0, stream>>>(deg, bsum, N);
    bsum_scan_kernel<<<1, 256, 0, stream>>>(bsum, nb, &row_start[N]);
    block_scan_kernel<<<nb, 256, 0, stream>>>(deg, bsum, row_start, cursor, N);
    if (gath)
        scatter_kernel<true><<<(E + 255) / 256, 256, 0, stream>>>(
            src, dst, cursor, perm, src_perm, edge_attr, ea_perm, E);
    else
        scatter_kernel<false><<<(E + 255) / 256, 256, 0, stream>>>(
            src, dst, cursor, perm, src_perm, edge_attr, ea_perm, E);
    starts_kernel<<<1, 512, 0, stream>>>(batch, starts, N, G);
    prep_weights<<<(8192 + 6 * 16384 + 255) / 256, 256, 0, stream>>>(Wp, conv_W1, conv_W2, wt);

    const unsigned short* Wp_hi = wt;
    const unsigned short* Wp_lo = wt + 8192;

    // h16 = bf16(x @ Wp + bp)
    gemm_mfma<64, false, false, true><<<gemmBlocks, 256, 0, stream>>>(
        x, Wp_hi, Wp_lo, bp, nullptr, nullptr, nullptr, h16, nullptr, N, invN);

    for (int l = 0; l < L; ++l) {
        float* sI = statsAll + l * 512;
        float* sO = sI + 256;
        const unsigned short* W1hi = wt + 16384 + (size_t)(2 * l) * 32768;
        const unsigned short* W1lo = W1hi + 16384;
        const unsigned short* W2hi = wt + 16384 + (size_t)(2 * l + 1) * 32768;
        const unsigned short* W2lo = W2hi + 16384;
        if (gath)
            aggregate_kernel<true><<<(N + 3) / 4, 256, 0, stream>>>(
                h16, ea_perm, perm, src_perm, row_start,
                conv_We + (size_t)l * EDIM * HID, conv_be + l * HID, t, N);
        else
            aggregate_kernel<false><<<(N + 3) / 4, 256, 0, stream>>>(
                h16, edge_attr, perm, src_perm, row_start,
                conv_We + (size_t)l * EDIM * HID, conv_be + l * HID, t, N);
        gemm_mfma<128, false, true, false><<<gemmBlocks, 256, 0, stream>>>(
            t, W1hi, W1lo, conv_b1 + l * HID,
            nullptr, nullptr, nullptr, t, sI, N, invN);
        gemm_mfma<128, true, true, false><<<gemmBlocks, 256, 0, stream>>>(
            t, W2hi, W2lo, conv_b2 + l * HID,
            sI, conv_g1 + l * HID, conv_bt1 + l * HID, t, sO, N, invN);
        bn_apply_pool<<<G, 512, 0, stream>>>(
            t, h16, sO, bn_g + l * HID, bn_b + l * HID, starts, z, l, invN);
    }

    head_gemm1<<<G, 128, 0, stream>>>(z, head_W1, head_b1, zr, msums);
    head_final<<<G, 128, 0, stream>>>(zr, msums, head_g, head_bt, head_W2, head_b2,
                                      (float*)d_out, invG);
}

// Round 13
// 679.256 us; speedup vs baseline: 1.1698x; 1.0077x over previous
//
#include <hip/hip_runtime.h>
#include <hip/hip_bf16.h>

#define HID 128
#define EDIM 16

typedef float v4f __attribute__((ext_vector_type(4)));
typedef float v2f __attribute__((ext_vector_type(2)));
typedef short s8v __attribute__((ext_vector_type(8)));   // 8 bf16 (4 VGPRs) MFMA frag
typedef float f4v __attribute__((ext_vector_type(4)));   // MFMA acc

#define MFMA_BF16(a, b, c) __builtin_amdgcn_mfma_f32_16x16x32_bf16((a), (b), (c), 0, 0, 0)

__device__ __forceinline__ unsigned short bf16_rne(float v)
{
    unsigned u = __builtin_bit_cast(unsigned, v);
    return (unsigned short)((u + 0x7fffu + ((u >> 16) & 1u)) >> 16);
}

__device__ __forceinline__ unsigned pack2(float lo, float hi)
{
    return (unsigned)bf16_rne(lo) | ((unsigned)bf16_rne(hi) << 16);
}

__device__ __forceinline__ float bflo(unsigned u) { return __builtin_bit_cast(float, u << 16); }
__device__ __forceinline__ float bfhi(unsigned u) { return __builtin_bit_cast(float, u & 0xffff0000u); }

__device__ __forceinline__ v2f unpack2(unsigned u)
{
    v2f r; r.x = bflo(u); r.y = bfhi(u); return r;
}

__device__ __forceinline__ void split_bf16(float v, unsigned short& h, unsigned short& l)
{
    unsigned u = __builtin_bit_cast(unsigned, v);
    unsigned hu = (u + 0x7fffu + ((u >> 16) & 1u)) >> 16;
    h = (unsigned short)hu;
    float hf = __builtin_bit_cast(float, hu << 16);
    l = bf16_rne(v - hf);
}

__device__ __forceinline__ v2f vmax0(v2f a)
{
    v2f r; r.x = fmaxf(a.x, 0.f); r.y = fmaxf(a.y, 0.f); return r;
}

// ================= CSR build =================
__global__ void hist_kernel(const int* __restrict__ dst, int* __restrict__ deg, int E)
{
    int e = blockIdx.x * 256 + threadIdx.x;
    if (e < E) atomicAdd(&deg[dst[e]], 1);
}

__global__ void block_sum_kernel(const int* __restrict__ deg, int* __restrict__ bsum, int Nn)
{
    int i = blockIdx.x * 256 + threadIdx.x;
    int v = (i < Nn) ? deg[i] : 0;
#pragma unroll
    for (int off = 32; off > 0; off >>= 1) v += __shfl_down(v, off, 64);
    __shared__ int ws[4];
    if ((threadIdx.x & 63) == 0) ws[threadIdx.x >> 6] = v;
    __syncthreads();
    if (threadIdx.x == 0) bsum[blockIdx.x] = ws[0] + ws[1] + ws[2] + ws[3];
}

__global__ void bsum_scan_kernel(int* bsum, int nb, int* total_out)
{
    __shared__ int sh[256];
    int tid = threadIdx.x;
    int v = (tid < nb) ? bsum[tid] : 0;
    sh[tid] = v;
    __syncthreads();
    for (int off = 1; off < 256; off <<= 1) {
        int tv = (tid >= off) ? sh[tid - off] : 0;
        __syncthreads();
        sh[tid] += tv;
        __syncthreads();
    }
    if (tid < nb) bsum[tid] = sh[tid] - v;
    if (tid == 255) *total_out = sh[255];
}

__global__ void block_scan_kernel(const int* __restrict__ deg, const int* __restrict__ bsum,
                                  int* __restrict__ row_start, int* __restrict__ cursor, int Nn)
{
    __shared__ int sh[256];
    int tid = threadIdx.x;
    int i = blockIdx.x * 256 + tid;
    int v = (i < Nn) ? deg[i] : 0;
    sh[tid] = v;
    __syncthreads();
    for (int off = 1; off < 256; off <<= 1) {
        int tv = (tid >= off) ? sh[tid - off] : 0;
        __syncthreads();
        sh[tid] += tv;
        __syncthreads();
    }
    if (i < Nn) {
        int excl = sh[tid] - v + bsum[blockIdx.x];
        row_start[i] = excl;
        cursor[i] = excl;
    }
}

// phase 1: permutation only (12B/edge traffic; scattered 4B writes live in L2)
__global__ void scatter_kernel(const int* __restrict__ src, const int* __restrict__ dst,
                               int* cursor, int* __restrict__ perm,
                               int* __restrict__ src_perm, int E)
{
    int e = blockIdx.x * 256 + threadIdx.x;
    if (e >= E) return;
    int pos = atomicAdd(&cursor[dst[e]], 1);
    perm[pos] = e;
    src_perm[pos] = src[e];
}

// phase 2: ea permute-copy — scattered READS (no RFO), fully coalesced writes.
// 4 threads per edge-row, each one float4.
__global__ void gather_ea_kernel(const float* __restrict__ ea, const int* __restrict__ perm,
                                 float* __restrict__ ea_perm, int E)
{
    int idx = blockIdx.x * 256 + threadIdx.x;
    int p = idx >> 2, c = (idx & 3) * 4;
    if (p >= E) return;
    int e = perm[p];
    *(float4*)&ea_perm[(size_t)p * EDIM + c] = *(const float4*)&ea[(size_t)e * EDIM + c];
}

// ================= weight prep: fp32 [K,128] -> transposed split-bf16 [128,K] hi/lo =================
__global__ void prep_weights(const float* __restrict__ Wp, const float* __restrict__ W1,
                             const float* __restrict__ W2, unsigned short* __restrict__ out)
{
    int idx = blockIdx.x * 256 + threadIdx.x;
    if (idx < 8192) {
        int n = idx >> 6, k = idx & 63;
        unsigned short h, l;
        split_bf16(Wp[k * 128 + n], h, l);
        out[idx] = h;
        out[8192 + idx] = l;
    } else {
        int j = idx - 8192;
        if (j >= 6 * 16384) return;
        int m2 = j >> 14;
        int r = j & 16383;
        int n = r >> 7, k = r & 127;
        int l = m2 >> 1;
        const float* Wsrc = (m2 & 1) ? (W2 + l * 16384) : (W1 + l * 16384);
        unsigned short h, lo;
        split_bf16(Wsrc[k * 128 + n], h, lo);
        int base = 16384 + m2 * 32768;
        out[base + r] = h;
        out[base + 16384 + r] = lo;
    }
}

// ====== Node-centric aggregation: 1 wave/node, 2 ch/lane; fp32 ea via scalar pipe, bf16 h gather ======
__device__ __forceinline__ void matvp(const v4f& a0, const v4f& a1,
                                      const v4f& a2, const v4f& a3,
                                      const v2f* __restrict__ w, v2f& m)
{
    m += w[0] * a0.x;  m += w[1] * a0.y;  m += w[2] * a0.z;  m += w[3] * a0.w;
    m += w[4] * a1.x;  m += w[5] * a1.y;  m += w[6] * a1.z;  m += w[7] * a1.w;
    m += w[8] * a2.x;  m += w[9] * a2.y;  m += w[10] * a2.z; m += w[11] * a2.w;
    m += w[12] * a3.x; m += w[13] * a3.y; m += w[14] * a3.z; m += w[15] * a3.w;
}

template<bool GATH>
__global__ __launch_bounds__(256, 8) void aggregate_kernel(
    const unsigned short* __restrict__ h16, const float* __restrict__ eaG,
    const int* __restrict__ perm, const int* __restrict__ src_perm,
    const int* __restrict__ row_start,
    const float* __restrict__ We, const float* __restrict__ be,
    float* __restrict__ t, int Nn)
{
    int tid = threadIdx.x;
    int lane = tid & 63;
    int c = lane * 2;
    v2f w[16];
#pragma unroll
    for (int k = 0; k < 16; ++k) w[k] = *(const v2f*)&We[k * HID + c];
    v2f bj = *(const v2f*)&be[c];
    int node = blockIdx.x * 4 + (tid >> 6);
    if (node >= Nn) return;
    const unsigned* __restrict__ hw = (const unsigned*)h16 + lane;  // bf16 ch-pair per lane
    v2f acc = unpack2(hw[(unsigned)node << 6]);
    int p0 = __builtin_amdgcn_readfirstlane(row_start[node]);
    int p1 = __builtin_amdgcn_readfirstlane(row_start[node + 1]);
    int p = p0;
    int s0 = 0, s1 = 0, s2 = 0, s3 = 0;
    if (p + 4 <= p1) { s0 = src_perm[p]; s1 = src_perm[p + 1]; s2 = src_perm[p + 2]; s3 = src_perm[p + 3]; }
    while (p + 4 <= p1) {
        int np = p + 4;
        int t0 = 0, t1 = 0, t2 = 0, t3 = 0;
        if (np + 4 <= p1) { t0 = src_perm[np]; t1 = src_perm[np + 1]; t2 = src_perm[np + 2]; t3 = src_perm[np + 3]; }
        // lane-varying h gather (one dword per lane per edge)
        unsigned hu0 = hw[(unsigned)s0 << 6];
        unsigned hu1 = hw[(unsigned)s1 << 6];
        unsigned hu2 = hw[(unsigned)s2 << 6];
        unsigned hu3 = hw[(unsigned)s3 << 6];
        // wave-uniform fp32 ea rows -> scalar pipe (no unpack)
        int q0, q1, q2, q3;
        if (GATH) { q0 = p; q1 = p + 1; q2 = p + 2; q3 = p + 3; }
        else      { q0 = perm[p]; q1 = perm[p + 1]; q2 = perm[p + 2]; q3 = perm[p + 3]; }
        const v4f* e0 = (const v4f*)(eaG + (size_t)(unsigned)q0 * EDIM);
        const v4f* e1 = (const v4f*)(eaG + (size_t)(unsigned)q1 * EDIM);
        const v4f* e2 = (const v4f*)(eaG + (size_t)(unsigned)q2 * EDIM);
        const v4f* e3 = (const v4f*)(eaG + (size_t)(unsigned)q3 * EDIM);
        v4f a00 = e0[0], a01 = e0[1], a02 = e0[2], a03 = e0[3];
        v4f a10 = e1[0], a11 = e1[1], a12 = e1[2], a13 = e1[3];
        v4f a20 = e2[0], a21 = e2[1], a22 = e2[2], a23 = e2[3];
        v4f a30 = e3[0], a31 = e3[1], a32 = e3[2], a33 = e3[3];
        v2f m0 = bj + unpack2(hu0), m1 = bj + unpack2(hu1);
        v2f m2 = bj + unpack2(hu2), m3 = bj + unpack2(hu3);
        matvp(a00, a01, a02, a03, w, m0);
        matvp(a10, a11, a12, a13, w, m1);
        matvp(a20, a21, a22, a23, w, m2);
        matvp(a30, a31, a32, a33, w, m3);
        acc += vmax0(m0) + vmax0(m1) + vmax0(m2) + vmax0(m3);
        p = np;
        s0 = t0; s1 = t1; s2 = t2; s3 = t3;
    }
    for (; p < p1; ++p) {
        int s = src_perm[p];
        int q = GATH ? p : perm[p];
        const v4f* e0 = (const v4f*)(eaG + (size_t)(unsigned)q * EDIM);
        v4f a0 = e0[0], a1 = e0[1], a2 = e0[2], a3 = e0[3];
        v2f m0 = bj + unpack2(hw[(unsigned)s << 6]);
        matvp(a0, a1, a2, a3, w, m0);
        acc += vmax0(m0);
    }
    *(v2f*)(t + ((unsigned)node << 7) + c) = acc;
}

// ================= split-bf16 MFMA GEMM =================
#define LPAD 40

template<int K, bool PRE_BN, bool POST_STATS, bool OUT_BF16>
__global__ __launch_bounds__(256) void gemm_mfma(
    const float* __restrict__ A, const unsigned short* __restrict__ Wh,
    const unsigned short* __restrict__ Wl, const float* __restrict__ bias,
    const float* __restrict__ preStats, const float* __restrict__ preG, const float* __restrict__ preB,
    void* __restrict__ Cout, float* __restrict__ postStats, int Nrows, float invN)
{
    __shared__ __align__(16) unsigned short Ah[128 * LPAD], Al[128 * LPAD];
    __shared__ __align__(16) unsigned short Bh[128 * LPAD], Bl[128 * LPAD];
    __shared__ float sc[PRE_BN ? K : 1], sb[PRE_BN ? K : 1];
    int tid = threadIdx.x;
    int rbase = blockIdx.x * 128;
    if (PRE_BN) {
        if (tid < K) {
            float mean = preStats[tid] * invN;
            float var = preStats[K + tid] * invN - mean * mean;
            float rstd = rsqrtf(var + 1e-5f);
            float g = preG[tid];
            sc[tid] = rstd * g;
            sb[tid] = preB[tid] - mean * rstd * g;
        }
        __syncthreads();
    }
    int w = tid >> 6, nl = tid & 15, q = (tid >> 4) & 3;
    f4v acc[2][8];
#pragma unroll
    for (int mt = 0; mt < 2; ++mt)
#pragma unroll
        for (int nt = 0; nt < 8; ++nt)
#pragma unroll
            for (int r = 0; r < 4; ++r) acc[mt][nt][r] = 0.f;

    for (int ks = 0; ks < K / 32; ++ks) {
        int k0 = ks * 32;
        if (ks) __syncthreads();
#pragma unroll
        for (int i = 0; i < 4; ++i) {
            int cidx = tid + i * 256;
            int m = cidx >> 3, k4 = (cidx & 7) * 4;
            int gr = rbase + m;
            float4 v = make_float4(0.f, 0.f, 0.f, 0.f);
            if (gr < Nrows) v = *(const float4*)&A[(size_t)gr * K + k0 + k4];
            if (PRE_BN) {
                v.x = fmaxf(v.x * sc[k0 + k4]     + sb[k0 + k4],     0.f);
                v.y = fmaxf(v.y * sc[k0 + k4 + 1] + sb[k0 + k4 + 1], 0.f);
                v.z = fmaxf(v.z * sc[k0 + k4 + 2] + sb[k0 + k4 + 2], 0.f);
                v.w = fmaxf(v.w * sc[k0 + k4 + 3] + sb[k0 + k4 + 3], 0.f);
            }
            unsigned short h0, l0, h1, l1, h2, l2, h3, l3;
            split_bf16(v.x, h0, l0); split_bf16(v.y, h1, l1);
            split_bf16(v.z, h2, l2); split_bf16(v.w, h3, l3);
            uint2 hp, lp;
            hp.x = (unsigned)h0 | ((unsigned)h1 << 16); hp.y = (unsigned)h2 | ((unsigned)h3 << 16);
            lp.x = (unsigned)l0 | ((unsigned)l1 << 16); lp.y = (unsigned)l2 | ((unsigned)l3 << 16);
            *(uint2*)&Ah[m * LPAD + k4] = hp;
            *(uint2*)&Al[m * LPAD + k4] = lp;
        }
#pragma unroll
        for (int i = 0; i < 2; ++i) {
            int g = tid + i * 256;
            int n = g >> 2, kq = (g & 3) * 8;
            uint4 hv = *(const uint4*)&Wh[(size_t)n * K + k0 + kq];
            uint4 lv = *(const uint4*)&Wl[(size_t)n * K + k0 + kq];
            *(uint4*)&Bh[n * LPAD + kq] = hv;
            *(uint4*)&Bl[n * LPAD + kq] = lv;
        }
        __syncthreads();
        s8v ah0 = *(const s8v*)&Ah[(w * 32 + nl) * LPAD + q * 8];
        s8v ah1 = *(const s8v*)&Ah[(w * 32 + 16 + nl) * LPAD + q * 8];
        s8v al0 = *(const s8v*)&Al[(w * 32 + nl) * LPAD + q * 8];
        s8v al1 = *(const s8v*)&Al[(w * 32 + 16 + nl) * LPAD + q * 8];
#pragma unroll
        for (int nt = 0; nt < 8; ++nt) {
            s8v bh = *(const s8v*)&Bh[(nt * 16 + nl) * LPAD + q * 8];
            s8v bl = *(const s8v*)&Bl[(nt * 16 + nl) * LPAD + q * 8];
            acc[0][nt] = MFMA_BF16(ah0, bh, acc[0][nt]);
            acc[0][nt] = MFMA_BF16(ah0, bl, acc[0][nt]);
            acc[0][nt] = MFMA_BF16(al0, bh, acc[0][nt]);
            acc[1][nt] = MFMA_BF16(ah1, bh, acc[1][nt]);
            acc[1][nt] = MFMA_BF16(ah1, bl, acc[1][nt]);
            acc[1][nt] = MFMA_BF16(al1, bh, acc[1][nt]);
        }
    }
    __syncthreads();

    float* Cf = (float*)Cout;
    unsigned short* Ch = (unsigned short*)Cout;
    float* redS = (float*)Ah;
    float* redQ = (float*)Al;
#pragma unroll
    for (int nt = 0; nt < 8; ++nt) {
        int col = nt * 16 + nl;
        float bcol = bias[col];
        float sv = 0.f, qv = 0.f;
#pragma unroll
        for (int mt = 0; mt < 2; ++mt) {
#pragma unroll
            for (int r = 0; r < 4; ++r) {
                int grow = rbase + w * 32 + mt * 16 + q * 4 + r;
                if (grow < Nrows) {
                    float o = acc[mt][nt][r] + bcol;
                    if (OUT_BF16) Ch[(size_t)grow * HID + col] = bf16_rne(o);
                    else          Cf[(size_t)grow * HID + col] = o;
                    if (POST_STATS) { sv += o; qv += o * o; }
                }
            }
        }
        if (POST_STATS) {
            sv += __shfl_down(sv, 32, 64); sv += __shfl_down(sv, 16, 64);
            qv += __shfl_down(qv, 32, 64); qv += __shfl_down(qv, 16, 64);
            if ((tid & 63) < 16) { redS[w * 128 + col] = sv; redQ[w * 128 + col] = qv; }
        }
    }
    if (POST_STATS) {
        __syncthreads();
        if (tid < 128) {
            float S = redS[tid] + redS[128 + tid] + redS[256 + tid] + redS[384 + tid];
            float Q = redQ[tid] + redQ[128 + tid] + redQ[256 + tid] + redQ[384 + tid];
            atomicAdd(&postStats[tid], S);
            atomicAdd(&postStats[128 + tid], Q);
        }
    }
}

// ======== fused BN apply + ReLU + pool; h stored as packed bf16 (pool uses exact fp32) ========
__global__ void bn_apply_pool(const float* __restrict__ X, unsigned short* __restrict__ h16,
                              const float* __restrict__ stats, const float* __restrict__ g,
                              const float* __restrict__ b, const int* __restrict__ starts,
                              float* __restrict__ z, int l, float invN)
{
    int gph = blockIdx.x;
    int tid = threadIdx.x;
    int ch4 = (tid & 31) * 4, wk = tid >> 5;   // 16 walkers x 32 lanes(float4)
    float sc[4], sh[4];
#pragma unroll
    for (int u = 0; u < 4; ++u) {
        int j = ch4 + u;
        float mean = stats[j] * invN;
        float var = stats[128 + j] * invN - mean * mean;
        float rstd = rsqrtf(var + 1e-5f);
        float gg = g[j];
        sc[u] = rstd * gg;
        sh[u] = b[j] - mean * rstd * gg;
    }
    int s = starts[gph], e = starts[gph + 1];
    float4 sum = make_float4(0.f, 0.f, 0.f, 0.f);
    float4 mx = make_float4(0.f, 0.f, 0.f, 0.f);
    unsigned* hv32 = (unsigned*)h16;
    for (int n = s + wk; n < e; n += 16) {
        float4 v = *(const float4*)&X[(size_t)n * HID + ch4];
        v.x = fmaxf(v.x * sc[0] + sh[0], 0.f);
        v.y = fmaxf(v.y * sc[1] + sh[1], 0.f);
        v.z = fmaxf(v.z * sc[2] + sh[2], 0.f);
        v.w = fmaxf(v.w * sc[3] + sh[3], 0.f);
        uint2 pk;
        pk.x = pack2(v.x, v.y);
        pk.y = pack2(v.z, v.w);
        *(uint2*)&hv32[(size_t)n * 64 + (ch4 >> 1)] = pk;
        sum.x += v.x; sum.y += v.y; sum.z += v.z; sum.w += v.w;
        mx.x = fmaxf(mx.x, v.x); mx.y = fmaxf(mx.y, v.y);
        mx.z = fmaxf(mx.z, v.z); mx.w = fmaxf(mx.w, v.w);
    }
    __shared__ float ls[16 * 128], lm[16 * 128];
    *(float4*)&ls[wk * 128 + ch4] = sum;
    *(float4*)&lm[wk * 128 + ch4] = mx;
    __syncthreads();
    if (tid < 128) {
        float S = 0.f, M = 0.f;
#pragma unroll
        for (int k = 0; k < 16; ++k) {
            S += ls[k * 128 + tid];
            M = fmaxf(M, lm[k * 128 + tid]);
        }
        float cnt = (float)(e - s);
        z[(size_t)gph * 768 + l * 128 + tid] = S / fmaxf(cnt, 1.f);
        z[(size_t)gph * 768 + 384 + l * 128 + tid] = M;
    }
}

// ================= segment boundaries (batch sorted) =================
__global__ void starts_kernel(const int* __restrict__ batch, int* __restrict__ starts,
                              int Nn, int Gn)
{
    int g = blockIdx.x * blockDim.x + threadIdx.x;
    if (g > Gn) return;
    int lo = 0, hi = Nn;
    while (lo < hi) { int mid = (lo + hi) >> 1; if (batch[mid] < g) lo = mid + 1; else hi = mid; }
    starts[g] = lo;
}

// ================= head =================
__global__ void head_gemm1(const float* __restrict__ z, const float* __restrict__ W,
                           const float* __restrict__ bias, float* __restrict__ zr,
                           float* __restrict__ msums)
{
    __shared__ __align__(16) float zl[768];
    int g = blockIdx.x, j = threadIdx.x;
    for (int i = j; i < 768; i += 128) zl[i] = z[(size_t)g * 768 + i];
    __syncthreads();
    float acc = bias[j];
    for (int k = 0; k < 768; k += 4) {
        float4 a4 = *(const float4*)&zl[k];
        acc += a4.x * W[k * 128 + j] + a4.y * W[(k + 1) * 128 + j]
             + a4.z * W[(k + 2) * 128 + j] + a4.w * W[(k + 3) * 128 + j];
    }
    zr[(size_t)g * 128 + j] = acc;
    atomicAdd(&msums[j], acc);
    atomicAdd(&msums[128 + j], acc * acc);
}

__global__ void head_final(const float* __restrict__ zr, const float* __restrict__ msums,
                           const float* __restrict__ hg, const float* __restrict__ hb,
                           const float* __restrict__ W2, const float* __restrict__ b2,
                           float* __restrict__ out, float invG)
{
    int g = blockIdx.x, j = threadIdx.x;
    float mean = msums[j] * invG;
    float var = msums[128 + j] * invG - mean * mean;
    float rstd = rsqrtf(var + 1e-5f);
    float v = zr[(size_t)g * 128 + j];
    v = (v - mean) * rstd * hg[j] + hb[j];
    v = fmaxf(v, 0.f);
    float p = v * W2[j];
#pragma unroll
    for (int off = 32; off > 0; off >>= 1) p += __shfl_down(p, off, 64);
    __shared__ float partial[2];
    if ((j & 63) == 0) partial[j >> 6] = p;
    __syncthreads();
    if (j == 0) out[g] = partial[0] + partial[1] + b2[0];
}

extern "C" void kernel_launch(void* const* d_in, const int* in_sizes, int n_in,
                              void* d_out, int out_size, void* d_ws, size_t ws_size,
                              hipStream_t stream)
{
    const float* x         = (const float*)d_in[0];
    const float* edge_attr = (const float*)d_in[1];
    const int*   src       = (const int*)d_in[2];
    const int*   dst       = (const int*)d_in[3];
    const int*   batch     = (const int*)d_in[4];
    const float* Wp        = (const float*)d_in[5];
    const float* bp        = (const float*)d_in[6];
    const float* conv_We   = (const float*)d_in[7];
    const float* conv_be   = (const float*)d_in[8];
    const float* conv_W1   = (const float*)d_in[9];
    const float* conv_b1   = (const float*)d_in[10];
    const float* conv_g1   = (const float*)d_in[11];
    const float* conv_bt1  = (const float*)d_in[12];
    const float* conv_W2   = (const float*)d_in[13];
    const float* conv_b2   = (const float*)d_in[14];
    const float* bn_g      = (const float*)d_in[15];
    const float* bn_b      = (const float*)d_in[16];
    const float* head_W1   = (const float*)d_in[17];
    const float* head_b1   = (const float*)d_in[18];
    const float* head_g    = (const float*)d_in[19];
    const float* head_bt   = (const float*)d_in[20];
    const float* head_W2   = (const float*)d_in[21];
    const float* head_b2   = (const float*)d_in[22];

    const int N = in_sizes[4];            // 50000
    const int E = in_sizes[2];            // 800000
    const int G = out_size;               // 256
    const int L = 3;

    // ---- workspace layout ----
    float* t        = (float*)d_ws;                  // N*128 fp32
    unsigned short* h16 = (unsigned short*)(t + (size_t)N * HID);  // N*128 bf16
    float* z        = (float*)(h16 + (size_t)N * HID);             // G*768
    float* zr       = z + (size_t)G * 768;           // G*128
    float* statsAll = zr + (size_t)G * HID;          // 7*256
    int*   deg      = (int*)(statsAll + 7 * 256);    // N
    int*   starts   = deg + N;                       // G+1
    int*   row_start= starts + (G + 1);              // N+1
    int*   cursor   = row_start + (N + 1);           // N
    int*   bsum     = cursor + N;                    // 256
    int*   src_perm = bsum + 256;                    // E
    int*   perm     = src_perm + E;                  // E
    unsigned short* wt = (unsigned short*)(perm + E);  // 212992 ushorts
    size_t base_end = (size_t)((char*)(wt + 212992) - (char*)d_ws);
    size_t ea_off = (base_end + 63) & ~(size_t)63;   // 64B-align ea rows
    bool gath = (ea_off + (size_t)E * EDIM * sizeof(float)) <= ws_size;
    float* ea_perm = (float*)((char*)d_ws + ea_off);
    float* msums = statsAll + 6 * 256;

    (void)n_in;

    const float invN = 1.0f / (float)N;
    const float invG = 1.0f / (float)G;
    const int nb = (N + 255) / 256;
    const int gemmBlocks = (N + 127) / 128;

    // ---- CSR build + weight prep ----
    (void)hipMemsetAsync(statsAll, 0, 7 * 256 * sizeof(float) + (size_t)N * sizeof(int), stream);
    hist_kernel<<<(E + 255) / 256, 256, 0, stream>>>(dst, deg, E);
    block_sum_kernel<<<nb, 256, 0, stream>>>(deg, bsum, N);
    bsum_scan_kernel<<<1, 256, 0, stream>>>(bsum, nb, &row_start[N]);
    block_scan_kernel<<<nb, 256, 0, stream>>>(deg, bsum, row_start, cursor, N);
    scatter_kernel<<<(E + 255) / 256, 256, 0, stream>>>(src, dst, cursor, perm, src_perm, E);
    if (gath)
        gather_ea_kernel<<<(E * 4 + 255) / 256, 256, 0, stream>>>(edge_attr, perm, ea_perm, E);
    starts_kernel<<<1, 512, 0, stream>>>(batch, starts, N, G);
    prep_weights<<<(8192 + 6 * 16384 + 255) / 256, 256, 0, stream>>>(Wp, conv_W1, conv_W2, wt);

    const unsigned short* Wp_hi = wt;
    const unsigned short* Wp_lo = wt + 8192;

    // h16 = bf16(x @ Wp + bp)
    gemm_mfma<64, false, false, true><<<gemmBlocks, 256, 0, stream>>>(
        x, Wp_hi, Wp_lo, bp, nullptr, nullptr, nullptr, h16, nullptr, N, invN);

    for (int l = 0; l < L; ++l) {
        float* sI = statsAll + l * 512;
        float* sO = sI + 256;
        const unsigned short* W1hi = wt + 16384 + (size_t)(2 * l) * 32768;
        const unsigned short* W1lo = W1hi + 16384;
        const unsigned short* W2hi = wt + 16384 + (size_t)(2 * l + 1) * 32768;
        const unsigned short* W2lo = W2hi + 16384;
        if (gath)
            aggregate_kernel<true><<<(N + 3) / 4, 256, 0, stream>>>(
                h16, ea_perm, perm, src_perm, row_start,
                conv_We + (size_t)l * EDIM * HID, conv_be + l * HID, t, N);
        else
            aggregate_kernel<false><<<(N + 3) / 4, 256, 0, stream>>>(
                h16, edge_attr, perm, src_perm, row_start,
                conv_We + (size_t)l * EDIM * HID, conv_be + l * HID, t, N);
        gemm_mfma<128, false, true, false><<<gemmBlocks, 256, 0, stream>>>(
            t, W1hi, W1lo, conv_b1 + l * HID,
            nullptr, nullptr, nullptr, t, sI, N, invN);
        gemm_mfma<128, true, true, false><<<gemmBlocks, 256, 0, stream>>>(
            t, W2hi, W2lo, conv_b2 + l * HID,
            sI, conv_g1 + l * HID, conv_bt1 + l * HID, t, sO, N, invN);
        bn_apply_pool<<<G, 512, 0, stream>>>(
            t, h16, sO, bn_g + l * HID, bn_b + l * HID, starts, z, l, invN);
    }

    head_gemm1<<<G, 128, 0, stream>>>(z, head_W1, head_b1, zr, msums);
    head_final<<<G, 128, 0, stream>>>(zr, msums, head_g, head_bt, head_W2, head_b2,
                                      (float*)d_out, invG);
}